// Round 6
// baseline (597.033 us; speedup 1.0000x reference)
//
#include <hip/hip_runtime.h>
#include <math.h>

#define B_ 128
#define G_ 16
#define A_ 8732
#define C_ 21
#define THR_ 0.5f
#define NEG_POS_ 3
#define VAR0_ 0.1f
#define VAR1_ 0.2f

#define BA_     (B_ * A_)          // 1,117,696
#define NBLKL_  (BA_ / 256)        // 4366 loss blocks, one anchor per thread
#define PCH_    ((NBLKL_ + B_ - 1) / B_)   // 35 partials per select slice
#define NPT_    35                 // ceil(8732/256) aux values per thread

struct Accum { float loss_loc; float loss_cls; int n_total; int done; int done2; int pad[3]; };

// ---------------------------------------------------------------------------
// K1: per-batch matching. One 512-thread block per batch. (verified verbatim)
// Block 0 additionally zeroes the accumulator (runs before K2 -> safe).
// ---------------------------------------------------------------------------
__global__ __launch_bounds__(512) void k_match(
    const float* __restrict__ tboxes,   // B,G,4 (point form)
    const int*   __restrict__ tlabels,  // B,G
    const float* __restrict__ anchors,  // A,4 (center form)
    int*         __restrict__ match,    // B*A packed conf|gt<<8
    int*         __restrict__ num_pos,  // B
    Accum*                    acc)
{
    const int b    = blockIdx.x;
    const int tid  = threadIdx.x;
    const int lane = tid & 63;
    const int w    = tid >> 6;          // 0..7

    if (b == 0 && tid == 0) {
        acc->loss_loc = 0.f;
        acc->loss_cls = 0.f;
        acc->n_total  = 0;
        acc->done     = 0;
        acc->done2    = 0;
    }

    __shared__ float         s_ov[A_];
    __shared__ unsigned char s_gi[A_];
    __shared__ float s_boxlds[G_ * 4];
    __shared__ int   s_lab[G_];
    __shared__ unsigned long long s_gb[8 * G_];
    __shared__ int   s_forced[G_];
    __shared__ int   s_cnt[8];

    if (tid < G_ * 4) s_boxlds[tid] = tboxes[b * G_ * 4 + tid];
    if (tid < G_)     s_lab[tid]    = tlabels[b * G_ + tid];
    __syncthreads();

    float bx0[G_], by0[G_], bx1[G_], by1[G_], bar[G_];
    #pragma unroll
    for (int g = 0; g < G_; ++g) {
        bx0[g] = s_boxlds[g * 4 + 0];
        by0[g] = s_boxlds[g * 4 + 1];
        bx1[g] = s_boxlds[g * 4 + 2];
        by1[g] = s_boxlds[g * 4 + 3];
        bar[g] = (bx1[g] - bx0[g]) * (by1[g] - by0[g]);
    }

    unsigned long long gb[G_];
    #pragma unroll
    for (int g = 0; g < G_; ++g) gb[g] = 0ull;

    for (int a = tid; a < A_; a += 512) {
        float4 an = ((const float4*)anchors)[a];
        float ax0 = an.x - an.z * 0.5f, ay0 = an.y - an.w * 0.5f;
        float ax1 = an.x + an.z * 0.5f, ay1 = an.y + an.w * 0.5f;
        float area_b = (ax1 - ax0) * (ay1 - ay0);
        float bov = -1.f; int bg = 0;
        #pragma unroll
        for (int g = 0; g < G_; ++g) {
            float tlx = fmaxf(bx0[g], ax0);
            float tly = fmaxf(by0[g], ay0);
            float brx = fminf(bx1[g], ax1);
            float bry = fminf(by1[g], ay1);
            float wdt = fmaxf(brx - tlx, 0.f);
            float hgt = fmaxf(bry - tly, 0.f);
            float inter = wdt * hgt;
            float iou = inter / (bar[g] + area_b - inter);
            if (iou > bov) { bov = iou; bg = g; }   // first g wins on ties
            unsigned long long pk =
                ((unsigned long long)__float_as_uint(iou) << 32) |
                (unsigned)(~(unsigned)a);           // max iou, min a on ties
            if (pk > gb[g]) gb[g] = pk;
        }
        s_ov[a] = bov;
        s_gi[a] = (unsigned char)bg;
    }

    #pragma unroll
    for (int g = 0; g < G_; ++g) {
        #pragma unroll
        for (int off = 32; off > 0; off >>= 1) {
            unsigned long long o = __shfl_down(gb[g], off);
            if (o > gb[g]) gb[g] = o;
        }
    }
    if (lane == 0) {
        #pragma unroll
        for (int g = 0; g < G_; ++g) s_gb[w * G_ + g] = gb[g];
    }
    __syncthreads();
    if (tid < G_) {
        unsigned long long m = 0ull;
        #pragma unroll
        for (int wv = 0; wv < 8; ++wv) {
            unsigned long long v = s_gb[wv * G_ + tid];
            if (v > m) m = v;
        }
        s_forced[tid] = (int)(~(unsigned)(m & 0xFFFFFFFFull));
    }
    __syncthreads();
    if (tid == 0) {
        for (int g = 0; g < G_; ++g) {      // ascending g, last write wins
            int a = s_forced[g];
            s_ov[a] = 1.0f;
            s_gi[a] = (unsigned char)g;
        }
    }
    __syncthreads();

    int cnt = 0;
    for (int a = tid; a < A_; a += 512) {
        float ov = s_ov[a];
        int g = s_gi[a];
        int conf = (ov < THR_) ? 0 : (s_lab[g] + 1);
        match[b * A_ + a] = conf | (g << 8);
        cnt += (conf > 0);
    }
    #pragma unroll
    for (int off = 32; off > 0; off >>= 1) cnt += __shfl_down(cnt, off);
    if (lane == 0) s_cnt[w] = cnt;
    __syncthreads();
    if (tid == 0) {
        int t = 0;
        #pragma unroll
        for (int wv = 0; wv < 8; ++wv) t += s_cnt[wv];
        num_pos[b] = t;
    }
}

// ---------------------------------------------------------------------------
// K2: per-anchor loss (verified body) + fused hard-negative mining.
// All 4366 blocks: loss for their 256-anchor slice; fence; increment done.
// The LAST 128 blocks to finish each claim one batch, spin until the grid
// drains (safe: >=4238 blocks already retired; ~1792-block residency >> 128
// spinners; no dispatch-order assumption), acquire-fence, then run the
// verified select body. done2 gates the single final out[] write.
// ---------------------------------------------------------------------------
__global__ __launch_bounds__(256) void k_loss_sel(
    const float* __restrict__ pred_off,   // B,A,4
    const float* __restrict__ pred_conf,  // B,A,C
    const float* __restrict__ tboxes,     // B,G,4
    const float* __restrict__ anchors,    // A,4
    const int*   __restrict__ match,      // flat BA
    const int*   __restrict__ num_pos,    // B
    float*       __restrict__ aux,        // flat BA
    float*       __restrict__ part_loc,   // NBLKL
    float*       __restrict__ part_cls,   // NBLKL
    Accum*                    acc,
    float*       __restrict__ out)
{
    const int tid  = threadIdx.x;
    const int i    = blockIdx.x * 256 + tid;   // flat anchor id, < BA_ (exact)
    const int lane = tid & 63;
    const int w    = tid >> 6;

    __shared__ float4 s_conf4[(256 * C_) / 4];   // 1344 float4 = 21504 B
    __shared__ float  s_lloc[4];
    __shared__ float  s_pnll[4];
    __shared__ int    s_c[2][4];
    __shared__ int    s_cf[4];
    __shared__ float  s_sf[4];
    __shared__ float  s_pl, s_pc;
    __shared__ int    s_old;

    // ================= loss body (verified) =================
    const float4* g4 = (const float4*)pred_conf + (size_t)blockIdx.x * (256 * C_ / 4);
    #pragma unroll
    for (int k = 0; k < 6; ++k) {
        int idx = tid + k * 256;
        if (idx < 256 * C_ / 4) s_conf4[idx] = g4[idx];
    }
    __syncthreads();

    const float* sc = (const float*)s_conf4 + tid * C_;

    int mk   = match[i];
    int conf = mk & 0xff;
    int g    = mk >> 8;

    float m = sc[0];
    #pragma unroll
    for (int c = 1; c < C_; ++c) m = fmaxf(m, sc[c]);
    float s = 0.f;
    #pragma unroll
    for (int c = 0; c < C_; ++c) s += __expf(sc[c] - m);
    float lse = m + __logf(s);

    float xc  = sc[conf];          // single dynamic LDS read
    float nll = lse - xc;
    bool  pos = conf > 0;

    float lloc = 0.f, pnll = 0.f;
    aux[i] = pos ? 0.f : nll;

    if (pos) {
        pnll = nll;
        int b = i / A_;            // const-div -> magic mul
        int a = i - b * A_;
        float4 an = ((const float4*)anchors)[a];
        float4 bx = ((const float4*)tboxes)[b * G_ + g];
        float gcx = (bx.x + bx.z) * 0.5f, gcy = (bx.y + bx.w) * 0.5f;
        float gw = bx.z - bx.x, gh = bx.w - bx.y;
        float l0 = (gcx - an.x) / (an.z * VAR0_);
        float l1 = (gcy - an.y) / (an.w * VAR0_);
        float l2 = logf(gw / an.z) / VAR1_;
        float l3 = logf(gh / an.w) / VAR1_;
        float4 p = ((const float4*)pred_off)[i];
        float d, ad;
        d = p.x - l0; ad = fabsf(d); lloc += (ad < 1.f) ? 0.5f * d * d : ad - 0.5f;
        d = p.y - l1; ad = fabsf(d); lloc += (ad < 1.f) ? 0.5f * d * d : ad - 0.5f;
        d = p.z - l2; ad = fabsf(d); lloc += (ad < 1.f) ? 0.5f * d * d : ad - 0.5f;
        d = p.w - l3; ad = fabsf(d); lloc += (ad < 1.f) ? 0.5f * d * d : ad - 0.5f;
    }

    #pragma unroll
    for (int off = 32; off > 0; off >>= 1) {
        lloc += __shfl_down(lloc, off);
        pnll += __shfl_down(pnll, off);
    }
    if (lane == 0) { s_lloc[w] = lloc; s_pnll[w] = pnll; }
    __syncthreads();
    if (tid == 0) {
        part_loc[blockIdx.x] = s_lloc[0] + s_lloc[1] + s_lloc[2] + s_lloc[3];
        part_cls[blockIdx.x] = s_pnll[0] + s_pnll[1] + s_pnll[2] + s_pnll[3];
    }

    // ============ completion protocol (release: aux/partials) ============
    __threadfence();                 // every thread: its aux store device-visible
    __syncthreads();                 // + tid0's partial stores done & fenced
    if (tid == 0) s_old = atomicAdd(&acc->done, 1);
    __syncthreads();
    const int old = s_old;
    if (old < NBLKL_ - B_) return;   // not among the last 128 finishers

    const int b = old - (NBLKL_ - B_);
    if (b >= B_) return;             // replay-safety guard (stale counter)

    if (tid == 0) {
        while (atomicAdd(&acc->done, 0) < NBLKL_) __builtin_amdgcn_s_sleep(10);
    }
    __syncthreads();
    __threadfence();                 // acquire: see all blocks' aux/partials

    // ================= select body (verified) for batch b =================
    {
        float L = 0.f, P = 0.f;
        int base = b * PCH_;
        if (tid < PCH_) {
            int idx = base + tid;
            if (idx < NBLKL_) { L = part_loc[idx]; P = part_cls[idx]; }
        }
        #pragma unroll
        for (int off = 32; off > 0; off >>= 1) {
            L += __shfl_down(L, off);
            P += __shfl_down(P, off);
        }
        if (tid == 0) { s_pl = L; s_pc = P; }
    }

    unsigned u[NPT_];
    #pragma unroll
    for (int j = 0; j < NPT_; ++j) {
        int a = tid + j * 256;
        u[j] = (a < A_) ? __float_as_uint(aux[(size_t)b * A_ + a]) : 0u;
    }

    const int npos = num_pos[b];
    const int K = min(NEG_POS_ * npos, A_ - 1);

    unsigned lo = 0u, hi = 0x7f800000u;
    int it = 0;
    while (lo < hi) {
        unsigned mid = (lo + hi) >> 1;
        int c = 0;
        #pragma unroll
        for (int j = 0; j < NPT_; ++j) c += (u[j] > mid);
        #pragma unroll
        for (int off = 32; off > 0; off >>= 1) c += __shfl_down(c, off);
        if (lane == 0) s_c[it & 1][w] = c;
        __syncthreads();
        int total = s_c[it & 1][0] + s_c[it & 1][1] + s_c[it & 1][2] + s_c[it & 1][3];
        if (total >= K) lo = mid + 1; else hi = mid;
        ++it;
    }
    // lo == bit pattern of T = K-th largest value

    int c = 0; float sm = 0.f;
    #pragma unroll
    for (int j = 0; j < NPT_; ++j) {
        if (u[j] > lo) { c++; sm += __uint_as_float(u[j]); }
    }
    #pragma unroll
    for (int off = 32; off > 0; off >>= 1) {
        c  += __shfl_down(c, off);
        sm += __shfl_down(sm, off);
    }
    if (lane == 0) { s_cf[w] = c; s_sf[w] = sm; }
    __syncthreads();

    if (tid == 0) {
        int   ct = s_cf[0] + s_cf[1] + s_cf[2] + s_cf[3];
        float st = s_sf[0] + s_sf[1] + s_sf[2] + s_sf[3];
        float T  = __uint_as_float(lo);

        atomicAdd(&acc->loss_loc, s_pl);
        atomicAdd(&acc->loss_cls, s_pc + st + (float)(K - ct) * T);
        atomicAdd(&acc->n_total,  npos);
        __threadfence();
        int o2 = atomicAdd(&acc->done2, 1);
        if (o2 == B_ - 1) {                     // last selector finalizes
            __threadfence();
            float llocT = atomicAdd(&acc->loss_loc, 0.f);
            float lclsT = atomicAdd(&acc->loss_cls, 0.f);
            float n     = (float)atomicAdd(&acc->n_total, 0);
            out[0] = llocT / n;
            out[1] = lclsT / n;
        }
    }
}

// ---------------------------------------------------------------------------
extern "C" void kernel_launch(void* const* d_in, const int* in_sizes, int n_in,
                              void* d_out, int out_size, void* d_ws, size_t ws_size,
                              hipStream_t stream) {
    const float* pred_off  = (const float*)d_in[0];  // B,A,4
    const float* pred_conf = (const float*)d_in[1];  // B,A,C
    const float* tboxes    = (const float*)d_in[2];  // B,G,4
    const int*   tlabels   = (const int*)  d_in[3];  // B,G
    const float* anchors   = (const float*)d_in[4];  // A,4
    float* out = (float*)d_out;

    // workspace layout (all 16B-aligned; fully rewritten every iteration)
    char* ws = (char*)d_ws;
    int*   match_ws = (int*)ws;     ws += (size_t)BA_ * sizeof(int);
    float* aux_ws   = (float*)ws;   ws += (size_t)BA_ * sizeof(float);
    float* ploc_ws  = (float*)ws;   ws += (size_t)((NBLKL_ + 3) & ~3) * sizeof(float);
    float* pcls_ws  = (float*)ws;   ws += (size_t)((NBLKL_ + 3) & ~3) * sizeof(float);
    int*   npos_ws  = (int*)ws;     ws += (size_t)((B_ + 3) & ~3) * sizeof(int);
    Accum* acc      = (Accum*)ws;

    k_match<<<B_, 512, 0, stream>>>(tboxes, tlabels, anchors, match_ws, npos_ws, acc);
    k_loss_sel<<<NBLKL_, 256, 0, stream>>>(pred_off, pred_conf, tboxes, anchors,
                                           match_ws, npos_ws, aux_ws,
                                           ploc_ws, pcls_ws, acc, out);
}

// Round 7
// 239.052 us; speedup vs baseline: 2.4975x; 2.4975x over previous
//
#include <hip/hip_runtime.h>
#include <math.h>

#define B_ 128
#define G_ 16
#define A_ 8732
#define C_ 21
#define THR_ 0.5f
#define NEG_POS_ 3
#define VAR0_ 0.1f
#define VAR1_ 0.2f

#define BA_     (B_ * A_)            // 1,117,696
#define CHUNK_  512                  // anchors per chunk
#define NCHUNK_ ((A_ + CHUNK_ - 1) / CHUNK_)   // 18 (17 full + 28-anchor tail)
#define TAILA_  (A_ - (NCHUNK_ - 1) * CHUNK_)  // 28
#define FULLV_  (CHUNK_ * C_ / 4)    // 2688 float4 per full chunk (43008 B)
#define TAILV_  (TAILA_ * C_ / 4)    // 147 float4
#define NPT_    NCHUNK_              // 18 aux values per thread in select

// async global->LDS, 16B/lane; dest is wave-uniform base + lane*16 (linear
// staging order). Only issued with wave-aligned full waves (guard idx<2688,
// 2688 = 42*64). Verified in R4 (absmax 0).
__device__ __forceinline__ void stage16(const float4* g, float4* l) {
    __builtin_amdgcn_global_load_lds(
        (const __attribute__((address_space(1))) void*)g,
        (__attribute__((address_space(3))) void*)l,
        16, 0, 0);
}

// ---------------------------------------------------------------------------
// K1: per-batch matching. One 512-thread block per batch. (verified verbatim)
// ---------------------------------------------------------------------------
__global__ __launch_bounds__(512) void k_match(
    const float* __restrict__ tboxes,   // B,G,4 (point form)
    const int*   __restrict__ tlabels,  // B,G
    const float* __restrict__ anchors,  // A,4 (center form)
    int*         __restrict__ match,    // B*A packed conf|gt<<8
    int*         __restrict__ num_pos)  // B
{
    const int b    = blockIdx.x;
    const int tid  = threadIdx.x;
    const int lane = tid & 63;
    const int w    = tid >> 6;          // 0..7

    __shared__ float         s_ov[A_];
    __shared__ unsigned char s_gi[A_];
    __shared__ float s_boxlds[G_ * 4];
    __shared__ int   s_lab[G_];
    __shared__ unsigned long long s_gb[8 * G_];
    __shared__ int   s_forced[G_];
    __shared__ int   s_cnt[8];

    if (tid < G_ * 4) s_boxlds[tid] = tboxes[b * G_ * 4 + tid];
    if (tid < G_)     s_lab[tid]    = tlabels[b * G_ + tid];
    __syncthreads();

    float bx0[G_], by0[G_], bx1[G_], by1[G_], bar[G_];
    #pragma unroll
    for (int g = 0; g < G_; ++g) {
        bx0[g] = s_boxlds[g * 4 + 0];
        by0[g] = s_boxlds[g * 4 + 1];
        bx1[g] = s_boxlds[g * 4 + 2];
        by1[g] = s_boxlds[g * 4 + 3];
        bar[g] = (bx1[g] - bx0[g]) * (by1[g] - by0[g]);
    }

    unsigned long long gb[G_];
    #pragma unroll
    for (int g = 0; g < G_; ++g) gb[g] = 0ull;

    for (int a = tid; a < A_; a += 512) {
        float4 an = ((const float4*)anchors)[a];
        float ax0 = an.x - an.z * 0.5f, ay0 = an.y - an.w * 0.5f;
        float ax1 = an.x + an.z * 0.5f, ay1 = an.y + an.w * 0.5f;
        float area_b = (ax1 - ax0) * (ay1 - ay0);
        float bov = -1.f; int bg = 0;
        #pragma unroll
        for (int g = 0; g < G_; ++g) {
            float tlx = fmaxf(bx0[g], ax0);
            float tly = fmaxf(by0[g], ay0);
            float brx = fminf(bx1[g], ax1);
            float bry = fminf(by1[g], ay1);
            float wdt = fmaxf(brx - tlx, 0.f);
            float hgt = fmaxf(bry - tly, 0.f);
            float inter = wdt * hgt;
            float iou = inter / (bar[g] + area_b - inter);
            if (iou > bov) { bov = iou; bg = g; }   // first g wins on ties
            unsigned long long pk =
                ((unsigned long long)__float_as_uint(iou) << 32) |
                (unsigned)(~(unsigned)a);           // max iou, min a on ties
            if (pk > gb[g]) gb[g] = pk;
        }
        s_ov[a] = bov;
        s_gi[a] = (unsigned char)bg;
    }

    #pragma unroll
    for (int g = 0; g < G_; ++g) {
        #pragma unroll
        for (int off = 32; off > 0; off >>= 1) {
            unsigned long long o = __shfl_down(gb[g], off);
            if (o > gb[g]) gb[g] = o;
        }
    }
    if (lane == 0) {
        #pragma unroll
        for (int g = 0; g < G_; ++g) s_gb[w * G_ + g] = gb[g];
    }
    __syncthreads();
    if (tid < G_) {
        unsigned long long m = 0ull;
        #pragma unroll
        for (int wv = 0; wv < 8; ++wv) {
            unsigned long long v = s_gb[wv * G_ + tid];
            if (v > m) m = v;
        }
        s_forced[tid] = (int)(~(unsigned)(m & 0xFFFFFFFFull));
    }
    __syncthreads();
    if (tid == 0) {
        for (int g = 0; g < G_; ++g) {      // ascending g, last write wins
            int a = s_forced[g];
            s_ov[a] = 1.0f;
            s_gi[a] = (unsigned char)g;
        }
    }
    __syncthreads();

    int cnt = 0;
    for (int a = tid; a < A_; a += 512) {
        float ov = s_ov[a];
        int g = s_gi[a];
        int conf = (ov < THR_) ? 0 : (s_lab[g] + 1);
        match[b * A_ + a] = conf | (g << 8);
        cnt += (conf > 0);
    }
    #pragma unroll
    for (int off = 32; off > 0; off >>= 1) cnt += __shfl_down(cnt, off);
    if (lane == 0) s_cnt[w] = cnt;
    __syncthreads();
    if (tid == 0) {
        int t = 0;
        #pragma unroll
        for (int wv = 0; wv < 8; ++wv) t += s_cnt[wv];
        num_pos[b] = t;
    }
}

// ---------------------------------------------------------------------------
// K2: per-batch fused loss + hard-negative mining. One 512-thread block per
// batch. Conf streamed through a 2x43KB LDS double-buffer via async
// global_load_lds (R4-verified staging); aux lives ONLY in LDS (35 KB);
// select = R2-verified 512-thread binary search from LDS. No aux global
// round-trip, no cold-path register arrays.
// ---------------------------------------------------------------------------
__global__ __launch_bounds__(512) void k_loss_sel(
    const float* __restrict__ pred_off,   // B,A,4
    const float* __restrict__ pred_conf,  // B,A,C
    const float* __restrict__ tboxes,     // B,G,4
    const float* __restrict__ anchors,    // A,4
    const int*   __restrict__ match,      // flat BA
    const int*   __restrict__ num_pos,    // B
    float*       __restrict__ lloc_b,     // B
    float*       __restrict__ lcls_b)     // B
{
    const int b    = blockIdx.x;
    const int tid  = threadIdx.x;
    const int lane = tid & 63;
    const int w    = tid >> 6;            // 0..7

    __shared__ float4 s_stage[2][FULLV_];     // 86016 B
    __shared__ float  s_aux[A_];              // 34928 B
    __shared__ int    s_c[2][8];
    __shared__ float  s_r0[8], s_r1[8], s_r3[8];
    __shared__ int    s_r2[8];

    float lloc = 0.f, pnll = 0.f;
    const float4* gb4 = (const float4*)pred_conf + (size_t)b * (A_ * C_ / 4);

    // prologue: async-stage chunk 0 into buf 0 (full chunk, wave-aligned)
    #pragma unroll
    for (int j = 0; j < 6; ++j) {
        int idx = tid + j * 512;
        if (idx < FULLV_) stage16(gb4 + idx, &s_stage[0][idx]);
    }
    int mkcur = match[(size_t)b * A_ + tid];
    __syncthreads();                          // vmcnt(0) drain: buf0 ready

    for (int cc = 0; cc < NCHUNK_; ++cc) {
        const int cur = cc & 1;
        const int nxt = cc + 1;
        int mknext = 0;
        if (nxt < NCHUNK_) {
            if (nxt < NCHUNK_ - 1) {
                // full chunk: async stage (guard 2688 = 42 waves, aligned)
                const float4* src = gb4 + (size_t)nxt * FULLV_;
                #pragma unroll
                for (int j = 0; j < 6; ++j) {
                    int idx = tid + j * 512;
                    if (idx < FULLV_) stage16(src + idx, &s_stage[cur ^ 1][idx]);
                }
            } else {
                // tail chunk (147 float4): plain stores, partial wave is fine
                const float4* src = gb4 + (size_t)nxt * FULLV_;
                if (tid < TAILV_) s_stage[cur ^ 1][tid] = src[tid];
            }
            int an = nxt * CHUNK_ + tid;
            if (an < A_) mknext = match[(size_t)b * A_ + an];
        }

        // ---- compute chunk cc from buf[cur] ----
        const int a = cc * CHUNK_ + tid;
        if (a < A_) {
            const float* sc = (const float*)&s_stage[cur][0] + tid * C_;
            float m = sc[0];
            #pragma unroll
            for (int c = 1; c < C_; ++c) m = fmaxf(m, sc[c]);
            float s = 0.f;
            #pragma unroll
            for (int c = 0; c < C_; ++c) s += __expf(sc[c] - m);
            float lse = m + __logf(s);

            int conf = mkcur & 0xff;
            int g    = mkcur >> 8;
            float xc  = sc[conf];             // single dynamic LDS read
            float nll = lse - xc;
            bool  pos = conf > 0;
            s_aux[a] = pos ? 0.f : nll;

            if (pos) {
                pnll += nll;
                float4 an4 = ((const float4*)anchors)[a];
                float4 bx  = ((const float4*)tboxes)[b * G_ + g];
                float gcx = (bx.x + bx.z) * 0.5f, gcy = (bx.y + bx.w) * 0.5f;
                float gw = bx.z - bx.x, gh = bx.w - bx.y;
                float l0 = (gcx - an4.x) / (an4.z * VAR0_);
                float l1 = (gcy - an4.y) / (an4.w * VAR0_);
                float l2 = logf(gw / an4.z) / VAR1_;
                float l3 = logf(gh / an4.w) / VAR1_;
                float4 p = ((const float4*)pred_off)[(size_t)b * A_ + a];
                float d, ad;
                d = p.x - l0; ad = fabsf(d); lloc += (ad < 1.f) ? 0.5f * d * d : ad - 0.5f;
                d = p.y - l1; ad = fabsf(d); lloc += (ad < 1.f) ? 0.5f * d * d : ad - 0.5f;
                d = p.z - l2; ad = fabsf(d); lloc += (ad < 1.f) ? 0.5f * d * d : ad - 0.5f;
                d = p.w - l3; ad = fabsf(d); lloc += (ad < 1.f) ? 0.5f * d * d : ad - 0.5f;
            }
        }

        __syncthreads();   // drains vmcnt/lgkmcnt: next buf staged, cur reads done
        mkcur = mknext;
    }

    // ================= select (R2-verified, 512 threads) =================
    unsigned u[NPT_];
    #pragma unroll
    for (int j = 0; j < NPT_; ++j) {
        int a = tid + j * 512;
        u[j] = (a < A_) ? __float_as_uint(s_aux[a]) : 0u;
    }

    const int npos = num_pos[b];
    const int K = min(NEG_POS_ * npos, A_ - 1);

    unsigned lo = 0u, hi = 0x7f800000u;
    int it = 0;
    while (lo < hi) {
        unsigned mid = (lo + hi) >> 1;
        int c = 0;
        #pragma unroll
        for (int j = 0; j < NPT_; ++j) c += (u[j] > mid);
        #pragma unroll
        for (int off = 32; off > 0; off >>= 1) c += __shfl_down(c, off);
        if (lane == 0) s_c[it & 1][w] = c;
        __syncthreads();
        int total = 0;
        #pragma unroll
        for (int wv = 0; wv < 8; ++wv) total += s_c[it & 1][wv];
        if (total >= K) lo = mid + 1; else hi = mid;
        ++it;
    }
    // lo == bit pattern of T = K-th largest aux value

    int selc = 0; float selsm = 0.f;
    #pragma unroll
    for (int j = 0; j < NPT_; ++j) {
        if (u[j] > lo) { selc++; selsm += __uint_as_float(u[j]); }
    }

    // ---- combined final reduce (loc, pnll, selc, selsm) ----
    #pragma unroll
    for (int off = 32; off > 0; off >>= 1) {
        lloc  += __shfl_down(lloc, off);
        pnll  += __shfl_down(pnll, off);
        selc  += __shfl_down(selc, off);
        selsm += __shfl_down(selsm, off);
    }
    if (lane == 0) { s_r0[w] = lloc; s_r1[w] = pnll; s_r2[w] = selc; s_r3[w] = selsm; }
    __syncthreads();
    if (tid == 0) {
        float L = 0.f, P = 0.f, S = 0.f; int Cc = 0;
        #pragma unroll
        for (int wv = 0; wv < 8; ++wv) {
            L += s_r0[wv]; P += s_r1[wv]; Cc += s_r2[wv]; S += s_r3[wv];
        }
        float T = __uint_as_float(lo);
        lloc_b[b] = L;
        lcls_b[b] = P + S + (float)(K - Cc) * T;
    }
}

// ---------------------------------------------------------------------------
// K3: finalize — reduce 128 per-batch partials. (R2-verified)
// ---------------------------------------------------------------------------
__global__ __launch_bounds__(128) void k_fin(
    const float* __restrict__ lloc_b,
    const float* __restrict__ lcls_b,
    const int*   __restrict__ npos_b,
    float*       __restrict__ out)
{
    const int tid  = threadIdx.x;
    const int lane = tid & 63;
    const int w    = tid >> 6;
    __shared__ float s_l[2], s_c[2];
    __shared__ int   s_n[2];

    float L = lloc_b[tid];
    float Cc = lcls_b[tid];
    int   n = npos_b[tid];
    #pragma unroll
    for (int off = 32; off > 0; off >>= 1) {
        L  += __shfl_down(L, off);
        Cc += __shfl_down(Cc, off);
        n  += __shfl_down(n, off);
    }
    if (lane == 0) { s_l[w] = L; s_c[w] = Cc; s_n[w] = n; }
    __syncthreads();
    if (tid == 0) {
        float ntot = (float)(s_n[0] + s_n[1]);
        out[0] = (s_l[0] + s_l[1]) / ntot;
        out[1] = (s_c[0] + s_c[1]) / ntot;
    }
}

// ---------------------------------------------------------------------------
extern "C" void kernel_launch(void* const* d_in, const int* in_sizes, int n_in,
                              void* d_out, int out_size, void* d_ws, size_t ws_size,
                              hipStream_t stream) {
    const float* pred_off  = (const float*)d_in[0];  // B,A,4
    const float* pred_conf = (const float*)d_in[1];  // B,A,C
    const float* tboxes    = (const float*)d_in[2];  // B,G,4
    const int*   tlabels   = (const int*)  d_in[3];  // B,G
    const float* anchors   = (const float*)d_in[4];  // A,4
    float* out = (float*)d_out;

    // workspace (all pieces fully rewritten every iteration -> re-poison safe)
    char* ws = (char*)d_ws;
    int*   match_ws = (int*)ws;   ws += (size_t)BA_ * sizeof(int);
    float* lloc_ws  = (float*)ws; ws += (size_t)B_ * sizeof(float);
    float* lcls_ws  = (float*)ws; ws += (size_t)B_ * sizeof(float);
    int*   npos_ws  = (int*)ws;

    k_match<<<B_, 512, 0, stream>>>(tboxes, tlabels, anchors, match_ws, npos_ws);
    k_loss_sel<<<B_, 512, 0, stream>>>(pred_off, pred_conf, tboxes, anchors,
                                       match_ws, npos_ws, lloc_ws, lcls_ws);
    k_fin<<<1, 128, 0, stream>>>(lloc_ws, lcls_ws, npos_ws, out);
}

// Round 8
// 217.230 us; speedup vs baseline: 2.7484x; 1.1005x over previous
//
#include <hip/hip_runtime.h>
#include <math.h>

#define B_ 128
#define G_ 16
#define A_ 8732
#define C_ 21
#define THR_ 0.5f
#define NEG_POS_ 3
#define VAR0_ 0.1f
#define VAR1_ 0.2f

#define BA_     (B_ * A_)          // 1,117,696
#define NBLKL_  (BA_ / 256)        // 4366 loss blocks, one anchor per thread
#define PCH_    ((NBLKL_ + B_ - 1) / B_)   // 35 partials per select slice
#define NPT_    35                 // ceil(8732/256) aux values per thread

typedef __attribute__((ext_vector_type(4))) float f32x4;

struct Accum { float loss_loc; float loss_cls; int n_total; int done; };

// ---------------------------------------------------------------------------
// K1: per-batch matching. One 512-thread block per batch. (verified verbatim)
// Block 0 additionally zeroes the accumulator (runs before K3 -> safe).
// ---------------------------------------------------------------------------
__global__ __launch_bounds__(512) void k_match(
    const float* __restrict__ tboxes,   // B,G,4 (point form)
    const int*   __restrict__ tlabels,  // B,G
    const float* __restrict__ anchors,  // A,4 (center form)
    int*         __restrict__ match,    // B*A packed conf|gt<<8
    int*         __restrict__ num_pos,  // B
    Accum*                    acc)
{
    const int b    = blockIdx.x;
    const int tid  = threadIdx.x;
    const int lane = tid & 63;
    const int w    = tid >> 6;          // 0..7

    if (b == 0 && tid == 0) {
        acc->loss_loc = 0.f;
        acc->loss_cls = 0.f;
        acc->n_total  = 0;
        acc->done     = 0;
    }

    __shared__ float         s_ov[A_];
    __shared__ unsigned char s_gi[A_];
    __shared__ float s_boxlds[G_ * 4];
    __shared__ int   s_lab[G_];
    __shared__ unsigned long long s_gb[8 * G_];
    __shared__ int   s_forced[G_];
    __shared__ int   s_cnt[8];

    if (tid < G_ * 4) s_boxlds[tid] = tboxes[b * G_ * 4 + tid];
    if (tid < G_)     s_lab[tid]    = tlabels[b * G_ + tid];
    __syncthreads();

    float bx0[G_], by0[G_], bx1[G_], by1[G_], bar[G_];
    #pragma unroll
    for (int g = 0; g < G_; ++g) {
        bx0[g] = s_boxlds[g * 4 + 0];
        by0[g] = s_boxlds[g * 4 + 1];
        bx1[g] = s_boxlds[g * 4 + 2];
        by1[g] = s_boxlds[g * 4 + 3];
        bar[g] = (bx1[g] - bx0[g]) * (by1[g] - by0[g]);
    }

    unsigned long long gb[G_];
    #pragma unroll
    for (int g = 0; g < G_; ++g) gb[g] = 0ull;

    for (int a = tid; a < A_; a += 512) {
        float4 an = ((const float4*)anchors)[a];
        float ax0 = an.x - an.z * 0.5f, ay0 = an.y - an.w * 0.5f;
        float ax1 = an.x + an.z * 0.5f, ay1 = an.y + an.w * 0.5f;
        float area_b = (ax1 - ax0) * (ay1 - ay0);
        float bov = -1.f; int bg = 0;
        #pragma unroll
        for (int g = 0; g < G_; ++g) {
            float tlx = fmaxf(bx0[g], ax0);
            float tly = fmaxf(by0[g], ay0);
            float brx = fminf(bx1[g], ax1);
            float bry = fminf(by1[g], ay1);
            float wdt = fmaxf(brx - tlx, 0.f);
            float hgt = fmaxf(bry - tly, 0.f);
            float inter = wdt * hgt;
            float iou = inter / (bar[g] + area_b - inter);
            if (iou > bov) { bov = iou; bg = g; }   // first g wins on ties
            unsigned long long pk =
                ((unsigned long long)__float_as_uint(iou) << 32) |
                (unsigned)(~(unsigned)a);           // max iou, min a on ties
            if (pk > gb[g]) gb[g] = pk;
        }
        s_ov[a] = bov;
        s_gi[a] = (unsigned char)bg;
    }

    #pragma unroll
    for (int g = 0; g < G_; ++g) {
        #pragma unroll
        for (int off = 32; off > 0; off >>= 1) {
            unsigned long long o = __shfl_down(gb[g], off);
            if (o > gb[g]) gb[g] = o;
        }
    }
    if (lane == 0) {
        #pragma unroll
        for (int g = 0; g < G_; ++g) s_gb[w * G_ + g] = gb[g];
    }
    __syncthreads();
    if (tid < G_) {
        unsigned long long m = 0ull;
        #pragma unroll
        for (int wv = 0; wv < 8; ++wv) {
            unsigned long long v = s_gb[wv * G_ + tid];
            if (v > m) m = v;
        }
        s_forced[tid] = (int)(~(unsigned)(m & 0xFFFFFFFFull));
    }
    __syncthreads();
    if (tid == 0) {
        for (int g = 0; g < G_; ++g) {      // ascending g, last write wins
            int a = s_forced[g];
            s_ov[a] = 1.0f;
            s_gi[a] = (unsigned char)g;
        }
    }
    __syncthreads();

    int cnt = 0;
    for (int a = tid; a < A_; a += 512) {
        float ov = s_ov[a];
        int g = s_gi[a];
        int conf = (ov < THR_) ? 0 : (s_lab[g] + 1);
        match[b * A_ + a] = conf | (g << 8);
        cnt += (conf > 0);
    }
    #pragma unroll
    for (int off = 32; off > 0; off >>= 1) cnt += __shfl_down(cnt, off);
    if (lane == 0) s_cnt[w] = cnt;
    __syncthreads();
    if (tid == 0) {
        int t = 0;
        #pragma unroll
        for (int wv = 0; wv < 8; ++wv) t += s_cnt[wv];
        num_pos[b] = t;
    }
}

// ---------------------------------------------------------------------------
// K2: per-anchor loss (R1/R5-verified body). ONE CHANGE vs R5: the two
// read-once streams (pred_conf staging, pred_off) use NON-TEMPORAL loads
// (nt flag, no L3 allocation) so the 94 MB conf stream does not force
// dirty-poison-line writebacks from L3 on the critical path.
// ---------------------------------------------------------------------------
__global__ __launch_bounds__(256) void k_loss(
    const float* __restrict__ pred_off,   // B,A,4
    const float* __restrict__ pred_conf,  // B,A,C
    const float* __restrict__ tboxes,     // B,G,4
    const float* __restrict__ anchors,    // A,4
    const int*   __restrict__ match,      // flat BA
    float*       __restrict__ aux,        // flat BA
    float*       __restrict__ part_loc,   // NBLKL
    float*       __restrict__ part_cls)   // NBLKL
{
    const int tid  = threadIdx.x;
    const int i    = blockIdx.x * 256 + tid;   // flat anchor id, < BA_ (exact)
    const int lane = tid & 63;
    const int w    = tid >> 6;

    __shared__ f32x4 s_conf4[(256 * C_) / 4];   // 1344 float4 = 21504 B
    __shared__ float s_lloc[4];
    __shared__ float s_pnll[4];

    // ---- coalesced nt staging: 1344 contiguous float4 per block ----
    const f32x4* g4 = (const f32x4*)pred_conf + (size_t)blockIdx.x * (256 * C_ / 4);
    #pragma unroll
    for (int k = 0; k < 6; ++k) {
        int idx = tid + k * 256;
        if (idx < 256 * C_ / 4) {
            f32x4 v = __builtin_nontemporal_load(g4 + idx);
            s_conf4[idx] = v;
        }
    }
    __syncthreads();

    const float* sc = (const float*)s_conf4 + tid * C_;

    int mk   = match[i];
    int conf = mk & 0xff;
    int g    = mk >> 8;

    float m = sc[0];
    #pragma unroll
    for (int c = 1; c < C_; ++c) m = fmaxf(m, sc[c]);
    float s = 0.f;
    #pragma unroll
    for (int c = 0; c < C_; ++c) s += __expf(sc[c] - m);
    float lse = m + __logf(s);

    float xc  = sc[conf];          // single dynamic LDS read
    float nll = lse - xc;
    bool  pos = conf > 0;

    float lloc = 0.f, pnll = 0.f;
    aux[i] = pos ? 0.f : nll;

    if (pos) {
        pnll = nll;
        int b = i / A_;            // const-div -> magic mul
        int a = i - b * A_;
        float4 an = ((const float4*)anchors)[a];
        float4 bx = ((const float4*)tboxes)[b * G_ + g];
        float gcx = (bx.x + bx.z) * 0.5f, gcy = (bx.y + bx.w) * 0.5f;
        float gw = bx.z - bx.x, gh = bx.w - bx.y;
        float l0 = (gcx - an.x) / (an.z * VAR0_);
        float l1 = (gcy - an.y) / (an.w * VAR0_);
        float l2 = logf(gw / an.z) / VAR1_;
        float l3 = logf(gh / an.w) / VAR1_;
        f32x4 p = __builtin_nontemporal_load((const f32x4*)pred_off + i);
        float d, ad;
        d = p.x - l0; ad = fabsf(d); lloc += (ad < 1.f) ? 0.5f * d * d : ad - 0.5f;
        d = p.y - l1; ad = fabsf(d); lloc += (ad < 1.f) ? 0.5f * d * d : ad - 0.5f;
        d = p.z - l2; ad = fabsf(d); lloc += (ad < 1.f) ? 0.5f * d * d : ad - 0.5f;
        d = p.w - l3; ad = fabsf(d); lloc += (ad < 1.f) ? 0.5f * d * d : ad - 0.5f;
    }

    #pragma unroll
    for (int off = 32; off > 0; off >>= 1) {
        lloc += __shfl_down(lloc, off);
        pnll += __shfl_down(pnll, off);
    }
    if (lane == 0) { s_lloc[w] = lloc; s_pnll[w] = pnll; }
    __syncthreads();
    if (tid == 0) {
        part_loc[blockIdx.x] = s_lloc[0] + s_lloc[1] + s_lloc[2] + s_lloc[3];
        part_cls[blockIdx.x] = s_pnll[0] + s_pnll[1] + s_pnll[2] + s_pnll[3];
    }
}

// ---------------------------------------------------------------------------
// K3: per-batch hard-negative mining (R5-verified verbatim) + fused final:
// slice-reduce of loss partials, 4 atomics per block, last block writes out.
// ---------------------------------------------------------------------------
__global__ __launch_bounds__(256) void k_select(
    const float* __restrict__ aux,
    const int*   __restrict__ num_pos,
    const float* __restrict__ part_loc,
    const float* __restrict__ part_cls,
    Accum*                    acc,
    float*       __restrict__ out)
{
    const int b    = blockIdx.x;
    const int tid  = threadIdx.x;
    const int lane = tid & 63;
    const int w    = tid >> 6;           // 0..3

    __shared__ int   s_c[2][4];
    __shared__ int   s_cf[4];
    __shared__ float s_sf[4];
    __shared__ float s_pl, s_pc;

    // ---- slice-reduce loss partials: entries [b*PCH_, b*PCH_+PCH_) ----
    {
        float L = 0.f, P = 0.f;
        int base = b * PCH_;
        if (tid < PCH_) {
            int idx = base + tid;
            if (idx < NBLKL_) { L = part_loc[idx]; P = part_cls[idx]; }
        }
        #pragma unroll
        for (int off = 32; off > 0; off >>= 1) {
            L += __shfl_down(L, off);
            P += __shfl_down(P, off);
        }
        if (tid == 0) { s_pl = L; s_pc = P; }
    }

    unsigned u[NPT_];
    #pragma unroll
    for (int j = 0; j < NPT_; ++j) {
        int a = tid + j * 256;
        u[j] = (a < A_) ? __float_as_uint(aux[(size_t)b * A_ + a]) : 0u;
    }

    const int npos = num_pos[b];
    const int K = min(NEG_POS_ * npos, A_ - 1);

    unsigned lo = 0u, hi = 0x7f800000u;
    int it = 0;
    while (lo < hi) {
        unsigned mid = (lo + hi) >> 1;
        int c = 0;
        #pragma unroll
        for (int j = 0; j < NPT_; ++j) c += (u[j] > mid);
        #pragma unroll
        for (int off = 32; off > 0; off >>= 1) c += __shfl_down(c, off);
        if (lane == 0) s_c[it & 1][w] = c;
        __syncthreads();
        int total = s_c[it & 1][0] + s_c[it & 1][1] + s_c[it & 1][2] + s_c[it & 1][3];
        if (total >= K) lo = mid + 1; else hi = mid;
        ++it;
    }
    // lo == bit pattern of T = K-th largest value

    int c = 0; float sm = 0.f;
    #pragma unroll
    for (int j = 0; j < NPT_; ++j) {
        if (u[j] > lo) { c++; sm += __uint_as_float(u[j]); }
    }
    #pragma unroll
    for (int off = 32; off > 0; off >>= 1) {
        c  += __shfl_down(c, off);
        sm += __shfl_down(sm, off);
    }
    if (lane == 0) { s_cf[w] = c; s_sf[w] = sm; }
    __syncthreads();

    if (tid == 0) {
        int   ct = s_cf[0] + s_cf[1] + s_cf[2] + s_cf[3];
        float st = s_sf[0] + s_sf[1] + s_sf[2] + s_sf[3];
        float T  = __uint_as_float(lo);

        atomicAdd(&acc->loss_loc, s_pl);
        atomicAdd(&acc->loss_cls, s_pc + st + (float)(K - ct) * T);
        atomicAdd(&acc->n_total,  npos);
        __threadfence();                         // release our adds
        int old = atomicAdd(&acc->done, 1);
        if (old == B_ - 1) {                     // last block finalizes
            __threadfence();                     // acquire all adds
            float lloc = atomicAdd(&acc->loss_loc, 0.f);
            float lcls = atomicAdd(&acc->loss_cls, 0.f);
            float n    = (float)atomicAdd(&acc->n_total, 0);
            out[0] = lloc / n;
            out[1] = lcls / n;
        }
    }
}

// ---------------------------------------------------------------------------
extern "C" void kernel_launch(void* const* d_in, const int* in_sizes, int n_in,
                              void* d_out, int out_size, void* d_ws, size_t ws_size,
                              hipStream_t stream) {
    const float* pred_off  = (const float*)d_in[0];  // B,A,4
    const float* pred_conf = (const float*)d_in[1];  // B,A,C
    const float* tboxes    = (const float*)d_in[2];  // B,G,4
    const int*   tlabels   = (const int*)  d_in[3];  // B,G
    const float* anchors   = (const float*)d_in[4];  // A,4
    float* out = (float*)d_out;

    // workspace layout (all 16B-aligned; fully rewritten every iteration)
    char* ws = (char*)d_ws;
    int*   match_ws = (int*)ws;     ws += (size_t)BA_ * sizeof(int);
    float* aux_ws   = (float*)ws;   ws += (size_t)BA_ * sizeof(float);
    float* ploc_ws  = (float*)ws;   ws += (size_t)((NBLKL_ + 3) & ~3) * sizeof(float);
    float* pcls_ws  = (float*)ws;   ws += (size_t)((NBLKL_ + 3) & ~3) * sizeof(float);
    int*   npos_ws  = (int*)ws;     ws += (size_t)((B_ + 3) & ~3) * sizeof(int);
    Accum* acc      = (Accum*)ws;

    k_match<<<B_, 512, 0, stream>>>(tboxes, tlabels, anchors, match_ws, npos_ws, acc);
    k_loss<<<NBLKL_, 256, 0, stream>>>(pred_off, pred_conf, tboxes, anchors,
                                       match_ws, aux_ws, ploc_ws, pcls_ws);
    k_select<<<B_, 256, 0, stream>>>(aux_ws, npos_ws, ploc_ws, pcls_ws, acc, out);
}